// Round 8
// baseline (750.231 us; speedup 1.0000x reference)
//
#include <hip/hip_runtime.h>
#include <math.h>

#define SEQ 2048
#define EMB 2048

typedef _Float16 f16;
typedef unsigned short ushort_t;
typedef __attribute__((ext_vector_type(2))) _Float16 f16x2;
typedef __attribute__((ext_vector_type(4))) _Float16 f16x4;
typedef __attribute__((ext_vector_type(8))) _Float16 f16x8;
typedef __attribute__((ext_vector_type(4))) float f32x4;
typedef __attribute__((ext_vector_type(16))) float f32x16;
typedef __attribute__((ext_vector_type(8))) short bf16x8;
typedef __attribute__((ext_vector_type(4))) unsigned short us4;
typedef __attribute__((ext_vector_type(8))) unsigned short us8;
typedef __attribute__((ext_vector_type(4))) unsigned int uint4v;

// async global->LDS, 16B per lane; LDS dest is lane-contiguous from lane0's ptr
__device__ __forceinline__ void gload16(const void* g, void* l) {
  __builtin_amdgcn_global_load_lds((const __attribute__((address_space(1))) unsigned int*)g,
                                   (__attribute__((address_space(3))) unsigned int*)l, 16, 0, 0);
}

__device__ __forceinline__ ushort_t f32_to_bf16(float f) {
  unsigned int u = __builtin_bit_cast(unsigned int, f);
  u += 0x7FFFu + ((u >> 16) & 1u);
  return (ushort_t)(u >> 16);
}

// packed f32x2 -> bf16x2 in one VALU op (RNE)
__device__ __forceinline__ unsigned cvt_pk_bf16_2(float lo, float hi) {
  unsigned r;
  asm("v_cvt_pk_bf16_f32 %0, %1, %2" : "=v"(r) : "v"(lo), "v"(hi));
  return r;
}

// ---------------- fp32 -> fp16 conversion, 5 tensors in one launch ----------------
__global__ __launch_bounds__(256) void cvt5_kernel(const float* __restrict__ i0,
                                                   const float* __restrict__ i1,
                                                   const float* __restrict__ i2,
                                                   const float* __restrict__ i3,
                                                   const float* __restrict__ i4,
                                                   f16* __restrict__ o0, f16* __restrict__ o1,
                                                   f16* __restrict__ o2, f16* __restrict__ o3,
                                                   f16* __restrict__ o4) {
  int b = blockIdx.x;
  int z = b >> 12;
  const float* in = (z == 0) ? i0 : (z == 1) ? i1 : (z == 2) ? i2 : (z == 3) ? i3 : i4;
  f16* out = (z == 0) ? o0 : (z == 1) ? o1 : (z == 2) ? o2 : (z == 3) ? o3 : o4;
  int i = ((b & 4095) * 256 + threadIdx.x) * 4;
  f32x4 v = *(const f32x4*)(in + i);
  *(f16x4*)(out + i) = __builtin_convertvector(v, f16x4);
}

// ---------------- RoPE tables (double precision, matches numpy) ----------------
__global__ __launch_bounds__(256) void rope_table_kernel(float* __restrict__ cosT,
                                                         float* __restrict__ sinT) {
  int id = blockIdx.x * 256 + threadIdx.x;
  int t = id >> 5, i = id & 31;
  double inv = pow(10000.0, -(double)i / 32.0);
  double ang = (double)t * inv;
  cosT[id] = (float)cos(ang);
  sinT[id] = (float)sin(ang);
}

// ---------------- Fused projection GEMM + RoPE epilogue, BK=32, swizzled LDS --------
// z=0 -> Q fragment-tiled qbT (rope + sqrt(128)*log2e scale)
// z=1 -> K fragment-tiled kbT (rope)
// z=2 -> V fragment-tiled vbT (bf16)
// Fragment layouts (all MFMA 32x32x16 operand tiles, 512 elems = 1 KB each):
//  qbT/kbT idx for X[t][h*128+d]:
//    ((h*64 + (t>>5))*8 + (d>>4))*512 + ((t&31) + ((d>>3)&1)*32)*8 + (d&7)
//  vbT idx for V[t][h*128+d] (kb=t>>6, kc=(t>>4)&3, hi8=(t>>3)&1, j=t&7, dt=d>>5):
//    (((h*32+kb)*4+kc)*4+dt)*512 + (((t>>3)&1)*32 + (d&31))*8 + (t&7)
__global__ __launch_bounds__(256, 3) void proj_gemm_kernel(
    const f16* __restrict__ A, const f16* __restrict__ B0, const f16* __restrict__ B1,
    const f16* __restrict__ B2, const float* __restrict__ cosT, const float* __restrict__ sinT,
    f16* __restrict__ qout, f16* __restrict__ kout, ushort_t* __restrict__ vtout) {
  const int z = blockIdx.z;
  const f16* __restrict__ B = (z == 0) ? B0 : ((z == 1) ? B1 : B2);
  __shared__ f16 As[128 * 32];
  __shared__ f16 Bs[128 * 32];
  const int tid = threadIdx.x;
  const int wave = tid >> 6, lane = tid & 63;
  const int l16 = lane & 15, quad = lane >> 4;
  const int wm = (wave >> 1) << 6, wn = (wave & 1) << 6;
  const int bm = blockIdx.y << 7, bn = blockIdx.x << 7;

  const int swg = ((lane & 3) ^ ((lane >> 3) & 3)) * 8;
  const f16* Ag = A + (size_t)(bm + wave * 32 + (lane >> 2)) * EMB + swg;
  const f16* Bg = B + (size_t)(bn + wave * 32 + (lane >> 2)) * EMB + swg;
  f16* Asl = &As[wave * 1024 + lane * 8];
  f16* Bsl = &Bs[wave * 1024 + lane * 8];

  const int swr = (quad ^ ((l16 >> 1) & 3)) * 8;
  int aoff[4], boff[4];
#pragma unroll
  for (int i = 0; i < 4; i++) {
    aoff[i] = (wm + i * 16 + l16) * 32 + swr;
    boff[i] = (wn + i * 16 + l16) * 32 + swr;
  }

  f32x4 acc[4][4];
#pragma unroll
  for (int i = 0; i < 4; i++)
#pragma unroll
    for (int j = 0; j < 4; j++) acc[i][j] = (f32x4){0.f, 0.f, 0.f, 0.f};

  for (int k0 = 0; k0 < EMB; k0 += 32) {
    __syncthreads();
    gload16(Ag + k0, Asl);
    gload16(Ag + (size_t)16 * EMB + k0, Asl + 512);
    gload16(Bg + k0, Bsl);
    gload16(Bg + (size_t)16 * EMB + k0, Bsl + 512);
    __syncthreads();
    f16x8 af[4], bf[4];
#pragma unroll
    for (int mi = 0; mi < 4; mi++) af[mi] = *(const f16x8*)&As[aoff[mi]];
#pragma unroll
    for (int ni = 0; ni < 4; ni++) bf[ni] = *(const f16x8*)&Bs[boff[ni]];
#pragma unroll
    for (int mi = 0; mi < 4; mi++)
#pragma unroll
      for (int ni = 0; ni < 4; ni++)
        acc[mi][ni] = __builtin_amdgcn_mfma_f32_16x16x32_f16(af[mi], bf[ni], acc[mi][ni], 0, 0, 0);
  }

  if (z == 2) {
#pragma unroll
    for (int mi = 0; mi < 4; mi++) {
#pragma unroll
      for (int ni = 0; ni < 4; ni++) {
        int row0 = bm + wm + mi * 16 + quad * 4;  // C/D: col=l16, row=quad*4+reg
        int col = bn + wn + ni * 16 + l16;
        us4 o;
#pragma unroll
        for (int rg = 0; rg < 4; rg++) o[rg] = f32_to_bf16(acc[mi][ni][rg]);
        int hidx = col >> 7, d = col & 127, t = row0;  // t..t+3 share all bits above t&7
        size_t idx = ((((size_t)hidx * 32 + (t >> 6)) * 4 + ((t >> 4) & 3)) * 4 + (d >> 5)) * 512 +
                     (((t >> 3) & 1) * 32 + (d & 31)) * 8 + (t & 7);
        *(us4*)&vtout[idx] = o;
      }
    }
  } else {
    f16* Co = (z == 0) ? qout : kout;
    const float scale = (z == 0) ? 16.3222307f : 1.0f;  // sqrt(128)*log2(e) folded into q
#pragma unroll
    for (int mi = 0; mi < 4; mi++) {
#pragma unroll
      for (int ni = 0; ni < 4; ni++) {
        int row0 = bm + wm + mi * 16 + quad * 4;
        int col = bn + wn + ni * 16 + l16;
        int i_r = (col & 63) >> 1;
        int odd = col & 1;  // = l16 & 1 (bn, wn, ni*16 even)
        int hidx = col >> 7, d = col & 127;
#pragma unroll
        for (int rg = 0; rg < 4; rg++) {
          int t = row0 + rg;
          float c = cosT[(t << 5) + i_r] * scale;
          float s = sinT[(t << 5) + i_r] * scale;
          float own = acc[mi][ni][rg];
          float other = __shfl_xor(own, 1);
          float xr = odd ? other : own;
          float xi = odd ? own : other;
          float outv = odd ? (xr * s + xi * c) : (xr * c - xi * s);
          size_t idx = ((size_t)((hidx * 64 + (t >> 5)) * 8 + (d >> 4))) * 512 +
                       ((t & 31) + ((d >> 3) & 1) * 32) * 8 + (d & 7);
          Co[idx] = (f16)outv;
        }
      }
    }
  }
}

// ---------------- Output GEMM: C = attn * wout^T, f32 out, 128x64 tiles, BK=32 ----------
__global__ __launch_bounds__(256, 2) void out_gemm_kernel(const f16* __restrict__ A,
                                                          const f16* __restrict__ B,
                                                          float* __restrict__ C) {
  __shared__ f16 As[128 * 32];
  __shared__ f16 Bs[64 * 32];
  const int tid = threadIdx.x;
  const int wave = tid >> 6, lane = tid & 63;
  const int l16 = lane & 15, quad = lane >> 4;
  const int wm = (wave >> 1) << 6, wn = (wave & 1) << 5;
  const int bm = blockIdx.y << 7, bn = blockIdx.x << 6;

  const int swg = ((lane & 3) ^ ((lane >> 3) & 3)) * 8;
  const f16* Ag = A + (size_t)(bm + wave * 32 + (lane >> 2)) * EMB + swg;
  const f16* Bg = B + (size_t)(bn + wave * 16 + (lane >> 2)) * EMB + swg;
  f16* Asl = &As[wave * 1024 + lane * 8];
  f16* Bsl = &Bs[wave * 512 + lane * 8];

  const int swr = (quad ^ ((l16 >> 1) & 3)) * 8;
  int aoff[4], boff[2];
#pragma unroll
  for (int i = 0; i < 4; i++) aoff[i] = (wm + i * 16 + l16) * 32 + swr;
#pragma unroll
  for (int i = 0; i < 2; i++) boff[i] = (wn + i * 16 + l16) * 32 + swr;

  f32x4 acc[4][2];
#pragma unroll
  for (int i = 0; i < 4; i++)
#pragma unroll
    for (int j = 0; j < 2; j++) acc[i][j] = (f32x4){0.f, 0.f, 0.f, 0.f};

  for (int k0 = 0; k0 < EMB; k0 += 32) {
    __syncthreads();
    gload16(Ag + k0, Asl);
    gload16(Ag + (size_t)16 * EMB + k0, Asl + 512);
    gload16(Bg + k0, Bsl);
    __syncthreads();
    f16x8 af[4], bf[2];
#pragma unroll
    for (int mi = 0; mi < 4; mi++) af[mi] = *(const f16x8*)&As[aoff[mi]];
#pragma unroll
    for (int ni = 0; ni < 2; ni++) bf[ni] = *(const f16x8*)&Bs[boff[ni]];
#pragma unroll
    for (int mi = 0; mi < 4; mi++)
#pragma unroll
      for (int ni = 0; ni < 2; ni++)
        acc[mi][ni] = __builtin_amdgcn_mfma_f32_16x16x32_f16(af[mi], bf[ni], acc[mi][ni], 0, 0, 0);
  }

#pragma unroll
  for (int mi = 0; mi < 4; mi++) {
#pragma unroll
    for (int ni = 0; ni < 2; ni++) {
      int row0 = bm + wm + mi * 16 + quad * 4;
      int col = bn + wn + ni * 16 + l16;
#pragma unroll
      for (int rg = 0; rg < 4; rg++)
        C[(size_t)(row0 + rg) * EMB + col] = acc[mi][ni][rg];
    }
  }
}

// ---------------- Differential attention v12: key-split waves, 4/SIMD ----------------
// 256 threads, 4 waves = (hh=wave>>1, ks=wave&1); block owns 32 q-rows; each wave
// computes its hh half over the ks-parity subset of the 64 32-key steps (32 steps).
// Grid (h 16, qblk 64) = 1024 blocks = 4/CU -> 16 waves/CU = 4/SIMD (VGPR<=128
// via __launch_bounds__(256,4); LDS 33KB epilogue-only fits 4 blocks/CU).
// Main loop: no LDS, no barriers; register ping-pong prefetch as v11.
// Partial O/lsum over ks are additive (fixed softmax bias, no running max);
// epilogue: lsum ks-combine -> O ks-combine -> cross-hh diff -> RMS -> store.
__global__ __launch_bounds__(256, 4) void diff_attn_v12(
    const f16* __restrict__ qbT, const f16* __restrict__ kbT, const ushort_t* __restrict__ vbT,
    const float* __restrict__ lq1, const float* __restrict__ lq2,
    const float* __restrict__ lk1, const float* __restrict__ lk2,
    const float* __restrict__ subw, f16* __restrict__ attnb) {
  const int h = blockIdx.x;  // head fastest -> heads stay L2-resident per XCD
  const int qblk = blockIdx.y;
  const int tid = threadIdx.x;
  const int wave = tid >> 6, lane = tid & 63;
  const int l32 = lane & 31, hi = lane >> 5;
  const int hh = wave >> 1, ks = wave & 1;

  __shared__ float OB[8192];       // 32 KB: 2 hh regions x (32q x 128d)
  __shared__ float lsb[2][2][32];  // [hh][ks][q]

  // ---- Q B-frags from qbT (coalesced tile loads; qblk is 32-row granular) ----
  const int qrow0 = qblk * 32;
  f16x8 qf[4];
  {
    const f16* qT = qbT + ((size_t)((h * 64 + qblk) * 8 + hh * 4)) * 512 + lane * 8;
#pragma unroll
    for (int c = 0; c < 4; c++) qf[c] = *(const f16x8*)(qT + c * 512);
  }

  f32x16 O[4];  // [dim-tile]; col=q=l32, row=(r&3)+8*(r>>2)+4*hi = dim within tile
#pragma unroll
  for (int dt = 0; dt < 4; dt++)
#pragma unroll
    for (int s2 = 0; s2 < 16; s2++) O[dt][s2] = 0.f;
  float lsum = 0.f;

  // ---- per-step fragment base pointers (advance 4096 elems per 32-key step) ----
  const f16* kT = kbT + ((size_t)(h * 64) * 8 + hh * 4) * 512 + lane * 8;
  const ushort_t* vT = vbT + (size_t)h * 262144 + lane * 8;

  auto loadK = [&](f16x8(&kr)[4], int it) {
    const f16* p = kT + (size_t)it * 4096;
#pragma unroll
    for (int c = 0; c < 4; c++) kr[c] = *(const f16x8*)(p + c * 512);
  };
  auto loadV = [&](us8(&vr)[8], int it) {
    const ushort_t* p = vT + (size_t)it * 4096;
#pragma unroll
    for (int T = 0; T < 8; T++) vr[T] = *(const us8*)(p + T * 512);
  };

  auto compute = [&](const f16x8(&kr)[4], const us8(&vr)[8]) {
    f32x16 acc;
#pragma unroll
    for (int s2 = 0; s2 < 16; s2++) acc[s2] = -28.8539008f;  // softmax bias in C-init
#pragma unroll
    for (int c = 0; c < 4; c++)
      acc = __builtin_amdgcn_mfma_f32_32x32x16_f16(kr[c], qf[c], acc, 0, 0, 0);
    float p[16];
#pragma unroll
    for (int s2 = 0; s2 < 16; s2++) p[s2] = __builtin_exp2f(acc[s2]);
    lsum += (((p[0] + p[1]) + (p[2] + p[3])) + ((p[4] + p[5]) + (p[6] + p[7]))) +
            (((p[8] + p[9]) + (p[10] + p[11])) + ((p[12] + p[13]) + (p[14] + p[15])));
    bf16x8 pf[2];
#pragma unroll
    for (int c2 = 0; c2 < 2; c2++) {
      unsigned w0 = cvt_pk_bf16_2(p[8 * c2 + 0], p[8 * c2 + 1]);
      unsigned w1 = cvt_pk_bf16_2(p[8 * c2 + 2], p[8 * c2 + 3]);
      unsigned w2 = cvt_pk_bf16_2(p[8 * c2 + 4], p[8 * c2 + 5]);
      unsigned w3 = cvt_pk_bf16_2(p[8 * c2 + 6], p[8 * c2 + 7]);
      asm("v_permlane32_swap_b32 %0, %1" : "+v"(w0), "+v"(w2));
      asm("v_permlane32_swap_b32 %0, %1" : "+v"(w1), "+v"(w3));
      uint4v pw;
      pw.x = w0; pw.y = w1; pw.z = w2; pw.w = w3;
      pf[c2] = __builtin_bit_cast(bf16x8, pw);
    }
    __builtin_amdgcn_s_setprio(1);
#pragma unroll
    for (int c2 = 0; c2 < 2; c2++) {
#pragma unroll
      for (int dt = 0; dt < 4; dt++) {
        bf16x8 vf = __builtin_bit_cast(bf16x8, vr[c2 * 4 + dt]);
        O[dt] = __builtin_amdgcn_mfma_f32_32x32x16_bf16(vf, pf[c2], O[dt], 0, 0, 0);
      }
    }
    __builtin_amdgcn_s_setprio(0);
  };

  // ---- register ping-pong pipeline over this wave's ks-parity steps ----
  // absolute step it = ks + 2*si, si = 0..31
  f16x8 kA[4], kB[4];
  us8 vA[8], vB[8];
  loadK(kA, ks);
  loadV(vA, ks);
  loadK(kB, ks + 2);
  loadV(vB, ks + 2);
  for (int si = 0; si < 32; si += 2) {
    compute(kA, vA);
    if (si + 2 < 32) {
      loadK(kA, ks + 2 * (si + 2));
      loadV(vA, ks + 2 * (si + 2));
    }
    compute(kB, vB);
    if (si + 3 < 32) {
      loadK(kB, ks + 2 * (si + 3));
      loadV(vB, ks + 2 * (si + 3));
    }
  }

  // ---- lambda ----
  float d1 = 0.f, d2 = 0.f;
  for (int i = 0; i < 64; i++) {
    d1 += lq1[i] * lk1[i];
    d2 += lq2[i] * lk2[i];
  }
  const float lam = __expf(d1) - __expf(d2) + 0.783605767f;

  // ---- denominators: combine hi-halves (shfl) then ks-halves (LDS) ----
  const float sp = lsum + __shfl_xor(lsum, 32);
  if (hi == 0) lsb[hh][ks][l32] = sp;
  __syncthreads();
  const float den = lsb[hh][0][l32] + lsb[hh][1][l32];
  const float inv = (hh == 0) ? (1.f / den) : (lam / den);

  // ---- scale own partial O; combine ks-halves through LDS ----
#pragma unroll
  for (int dt = 0; dt < 4; dt++)
#pragma unroll
    for (int s2 = 0; s2 < 16; s2++) O[dt][s2] *= inv;

  auto obIdx = [&](int hhR, int dt, int rq) { return (((hhR * 4 + dt) * 4 + rq) * 64 + lane) * 4; };

  if (ks == 1) {
#pragma unroll
    for (int dt = 0; dt < 4; dt++)
#pragma unroll
      for (int rq = 0; rq < 4; rq++) {
        f32x4 v;
#pragma unroll
        for (int rg = 0; rg < 4; rg++) v[rg] = O[dt][rq * 4 + rg];
        *(f32x4*)&OB[obIdx(hh, dt, rq)] = v;
      }
  }
  __syncthreads();
  if (ks == 0) {
#pragma unroll
    for (int dt = 0; dt < 4; dt++)
#pragma unroll
      for (int rq = 0; rq < 4; rq++) {
        f32x4 v1 = *(const f32x4*)&OB[obIdx(hh, dt, rq)];
#pragma unroll
        for (int rg = 0; rg < 4; rg++) O[dt][rq * 4 + rg] += v1[rg];
      }
  }
  __syncthreads();
  // ---- hh=1 (ks=0) publishes combined O1; hh=0 (ks=0) computes diff+RMS+store ----
  if (ks == 0 && hh == 1) {
#pragma unroll
    for (int dt = 0; dt < 4; dt++)
#pragma unroll
      for (int rq = 0; rq < 4; rq++) {
        f32x4 v;
#pragma unroll
        for (int rg = 0; rg < 4; rg++) v[rg] = O[dt][rq * 4 + rg];
        *(f32x4*)&OB[obIdx(1, dt, rq)] = v;
      }
  }
  __syncthreads();
  if (ks == 0 && hh == 0) {
    float a[4][16];
    float ms = 0.f;
#pragma unroll
    for (int dt = 0; dt < 4; dt++)
#pragma unroll
      for (int rq = 0; rq < 4; rq++) {
        f32x4 o1 = *(const f32x4*)&OB[obIdx(1, dt, rq)];
#pragma unroll
        for (int rg = 0; rg < 4; rg++) {
          float v = O[dt][rq * 4 + rg] - o1[rg];
          a[dt][rq * 4 + rg] = v;
          ms += v * v;
        }
      }
    ms += __shfl_xor(ms, 32);
    const float rms = rsqrtf(ms * (1.f / 128.f) + 1e-5f);
    const int t_g = qrow0 + l32;
#pragma unroll
    for (int dt = 0; dt < 4; dt++)
#pragma unroll
      for (int rq = 0; rq < 4; rq++) {
        f32x4 sw = *(const f32x4*)(subw + dt * 32 + rq * 8 + hi * 4);
        f16x4 o;
#pragma unroll
        for (int rg = 0; rg < 4; rg++) o[rg] = (f16)(a[dt][rq * 4 + rg] * rms * sw[rg]);
        *(f16x4*)(attnb + (size_t)t_g * EMB + h * 128 + dt * 32 + rq * 8 + hi * 4) = o;
      }
  }
}

// ---------------- launcher ----------------
extern "C" void kernel_launch(void* const* d_in, const int* in_sizes, int n_in,
                              void* d_out, int out_size, void* d_ws, size_t ws_size,
                              hipStream_t stream) {
  const float* x    = (const float*)d_in[0];
  const float* wq   = (const float*)d_in[1];
  const float* wk   = (const float*)d_in[2];
  const float* wv   = (const float*)d_in[3];
  const float* wout = (const float*)d_in[4];
  const float* lq1  = (const float*)d_in[5];
  const float* lq2  = (const float*)d_in[6];
  const float* lk1  = (const float*)d_in[7];
  const float* lk2  = (const float*)d_in[8];
  const float* subw = (const float*)d_in[9];
  float* out = (float*)d_out;

  char* ws = (char*)d_ws;
  const size_t MB = 1024 * 1024;
  f16* xb    = (f16*)(ws + 0 * MB);
  f16* wqb   = (f16*)(ws + 8 * MB);
  f16* wkb   = (f16*)(ws + 16 * MB);
  f16* wvb   = (f16*)(ws + 24 * MB);
  f16* woutb = (f16*)(ws + 32 * MB);
  f16* qbT   = (f16*)(ws + 40 * MB);  // f16, fragment-tiled per head (rope'd, scaled)
  f16* kbT   = (f16*)(ws + 48 * MB);  // f16, fragment-tiled per head (rope'd)
  ushort_t* vbT = (ushort_t*)(ws + 56 * MB);  // bf16, fragment-tiled per head
  f16* attnb = (f16*)(ws + 64 * MB);
  float* cosT = (float*)(ws + 72 * MB);
  float* sinT = (float*)(ws + 72 * MB + 262144);

  dim3 b256(256);
  cvt5_kernel<<<5 * 4096, b256, 0, stream>>>(x, wq, wk, wv, wout, xb, wqb, wkb, wvb, woutb);
  rope_table_kernel<<<256, b256, 0, stream>>>(cosT, sinT);

  proj_gemm_kernel<<<dim3(16, 16, 3), b256, 0, stream>>>(xb, wqb, wkb, wvb, cosT, sinT, qbT, kbT,
                                                         vbT);

  diff_attn_v12<<<dim3(16, 64), b256, 0, stream>>>(qbT, kbT, vbT, lq1, lq2, lk1, lk2, subw,
                                                   attnb);

  out_gemm_kernel<<<dim3(32, 16), b256, 0, stream>>>(attnb, woutb, out);
}

// Round 9
// 327.504 us; speedup vs baseline: 2.2908x; 2.2908x over previous
//
#include <hip/hip_runtime.h>
#include <math.h>

#define SEQ 2048
#define EMB 2048

typedef _Float16 f16;
typedef unsigned short ushort_t;
typedef __attribute__((ext_vector_type(2))) _Float16 f16x2;
typedef __attribute__((ext_vector_type(4))) _Float16 f16x4;
typedef __attribute__((ext_vector_type(8))) _Float16 f16x8;
typedef __attribute__((ext_vector_type(4))) float f32x4;
typedef __attribute__((ext_vector_type(16))) float f32x16;
typedef __attribute__((ext_vector_type(8))) short bf16x8;
typedef __attribute__((ext_vector_type(4))) unsigned short us4;
typedef __attribute__((ext_vector_type(8))) unsigned short us8;
typedef __attribute__((ext_vector_type(4))) unsigned int uint4v;

// async global->LDS, 16B per lane; LDS dest is lane-contiguous from lane0's ptr
__device__ __forceinline__ void gload16(const void* g, void* l) {
  __builtin_amdgcn_global_load_lds((const __attribute__((address_space(1))) unsigned int*)g,
                                   (__attribute__((address_space(3))) unsigned int*)l, 16, 0, 0);
}

__device__ __forceinline__ ushort_t f32_to_bf16(float f) {
  unsigned int u = __builtin_bit_cast(unsigned int, f);
  u += 0x7FFFu + ((u >> 16) & 1u);
  return (ushort_t)(u >> 16);
}

// packed f32x2 -> bf16x2 in one VALU op (RNE)
__device__ __forceinline__ unsigned cvt_pk_bf16_2(float lo, float hi) {
  unsigned r;
  asm("v_cvt_pk_bf16_f32 %0, %1, %2" : "=v"(r) : "v"(lo), "v"(hi));
  return r;
}

// ---------------- fp32 -> fp16 conversion, 5 tensors in one launch ----------------
__global__ __launch_bounds__(256) void cvt5_kernel(const float* __restrict__ i0,
                                                   const float* __restrict__ i1,
                                                   const float* __restrict__ i2,
                                                   const float* __restrict__ i3,
                                                   const float* __restrict__ i4,
                                                   f16* __restrict__ o0, f16* __restrict__ o1,
                                                   f16* __restrict__ o2, f16* __restrict__ o3,
                                                   f16* __restrict__ o4) {
  int b = blockIdx.x;
  int z = b >> 12;
  const float* in = (z == 0) ? i0 : (z == 1) ? i1 : (z == 2) ? i2 : (z == 3) ? i3 : i4;
  f16* out = (z == 0) ? o0 : (z == 1) ? o1 : (z == 2) ? o2 : (z == 3) ? o3 : o4;
  int i = ((b & 4095) * 256 + threadIdx.x) * 4;
  f32x4 v = *(const f32x4*)(in + i);
  *(f16x4*)(out + i) = __builtin_convertvector(v, f16x4);
}

// ---------------- RoPE tables (double precision, matches numpy) ----------------
__global__ __launch_bounds__(256) void rope_table_kernel(float* __restrict__ cosT,
                                                         float* __restrict__ sinT) {
  int id = blockIdx.x * 256 + threadIdx.x;
  int t = id >> 5, i = id & 31;
  double inv = pow(10000.0, -(double)i / 32.0);
  double ang = (double)t * inv;
  cosT[id] = (float)cos(ang);
  sinT[id] = (float)sin(ang);
}

// ---------------- Fused projection GEMM + RoPE epilogue, BK=32, swizzled LDS --------
// z=0 -> Q fragment-tiled qbT (rope + sqrt(128)*log2e scale)
// z=1 -> K fragment-tiled kbT (rope)
// z=2 -> V fragment-tiled vbT (bf16)
// Fragment layouts (all MFMA 32x32x16 operand tiles, 512 elems = 1 KB each):
//  qbT/kbT idx for X[t][h*128+d]:
//    ((h*64 + (t>>5))*8 + (d>>4))*512 + ((t&31) + ((d>>3)&1)*32)*8 + (d&7)
//  vbT idx for V[t][h*128+d] (kb=t>>6, kc=(t>>4)&3, hi8=(t>>3)&1, j=t&7, dt=d>>5):
//    (((h*32+kb)*4+kc)*4+dt)*512 + (((t>>3)&1)*32 + (d&31))*8 + (t&7)
__global__ __launch_bounds__(256, 3) void proj_gemm_kernel(
    const f16* __restrict__ A, const f16* __restrict__ B0, const f16* __restrict__ B1,
    const f16* __restrict__ B2, const float* __restrict__ cosT, const float* __restrict__ sinT,
    f16* __restrict__ qout, f16* __restrict__ kout, ushort_t* __restrict__ vtout) {
  const int z = blockIdx.z;
  const f16* __restrict__ B = (z == 0) ? B0 : ((z == 1) ? B1 : B2);
  __shared__ f16 As[128 * 32];
  __shared__ f16 Bs[128 * 32];
  const int tid = threadIdx.x;
  const int wave = tid >> 6, lane = tid & 63;
  const int l16 = lane & 15, quad = lane >> 4;
  const int wm = (wave >> 1) << 6, wn = (wave & 1) << 6;
  const int bm = blockIdx.y << 7, bn = blockIdx.x << 7;

  const int swg = ((lane & 3) ^ ((lane >> 3) & 3)) * 8;
  const f16* Ag = A + (size_t)(bm + wave * 32 + (lane >> 2)) * EMB + swg;
  const f16* Bg = B + (size_t)(bn + wave * 32 + (lane >> 2)) * EMB + swg;
  f16* Asl = &As[wave * 1024 + lane * 8];
  f16* Bsl = &Bs[wave * 1024 + lane * 8];

  const int swr = (quad ^ ((l16 >> 1) & 3)) * 8;
  int aoff[4], boff[4];
#pragma unroll
  for (int i = 0; i < 4; i++) {
    aoff[i] = (wm + i * 16 + l16) * 32 + swr;
    boff[i] = (wn + i * 16 + l16) * 32 + swr;
  }

  f32x4 acc[4][4];
#pragma unroll
  for (int i = 0; i < 4; i++)
#pragma unroll
    for (int j = 0; j < 4; j++) acc[i][j] = (f32x4){0.f, 0.f, 0.f, 0.f};

  for (int k0 = 0; k0 < EMB; k0 += 32) {
    __syncthreads();
    gload16(Ag + k0, Asl);
    gload16(Ag + (size_t)16 * EMB + k0, Asl + 512);
    gload16(Bg + k0, Bsl);
    gload16(Bg + (size_t)16 * EMB + k0, Bsl + 512);
    __syncthreads();
    f16x8 af[4], bf[4];
#pragma unroll
    for (int mi = 0; mi < 4; mi++) af[mi] = *(const f16x8*)&As[aoff[mi]];
#pragma unroll
    for (int ni = 0; ni < 4; ni++) bf[ni] = *(const f16x8*)&Bs[boff[ni]];
#pragma unroll
    for (int mi = 0; mi < 4; mi++)
#pragma unroll
      for (int ni = 0; ni < 4; ni++)
        acc[mi][ni] = __builtin_amdgcn_mfma_f32_16x16x32_f16(af[mi], bf[ni], acc[mi][ni], 0, 0, 0);
  }

  if (z == 2) {
#pragma unroll
    for (int mi = 0; mi < 4; mi++) {
#pragma unroll
      for (int ni = 0; ni < 4; ni++) {
        int row0 = bm + wm + mi * 16 + quad * 4;  // C/D: col=l16, row=quad*4+reg
        int col = bn + wn + ni * 16 + l16;
        us4 o;
#pragma unroll
        for (int rg = 0; rg < 4; rg++) o[rg] = f32_to_bf16(acc[mi][ni][rg]);
        int hidx = col >> 7, d = col & 127, t = row0;  // t..t+3 share all bits above t&7
        size_t idx = ((((size_t)hidx * 32 + (t >> 6)) * 4 + ((t >> 4) & 3)) * 4 + (d >> 5)) * 512 +
                     (((t >> 3) & 1) * 32 + (d & 31)) * 8 + (t & 7);
        *(us4*)&vtout[idx] = o;
      }
    }
  } else {
    f16* Co = (z == 0) ? qout : kout;
    const float scale = (z == 0) ? 16.3222307f : 1.0f;  // sqrt(128)*log2(e) folded into q
#pragma unroll
    for (int mi = 0; mi < 4; mi++) {
#pragma unroll
      for (int ni = 0; ni < 4; ni++) {
        int row0 = bm + wm + mi * 16 + quad * 4;
        int col = bn + wn + ni * 16 + l16;
        int i_r = (col & 63) >> 1;
        int odd = col & 1;  // = l16 & 1 (bn, wn, ni*16 even)
        int hidx = col >> 7, d = col & 127;
#pragma unroll
        for (int rg = 0; rg < 4; rg++) {
          int t = row0 + rg;
          float c = cosT[(t << 5) + i_r] * scale;
          float s = sinT[(t << 5) + i_r] * scale;
          float own = acc[mi][ni][rg];
          float other = __shfl_xor(own, 1);
          float xr = odd ? other : own;
          float xi = odd ? own : other;
          float outv = odd ? (xr * s + xi * c) : (xr * c - xi * s);
          size_t idx = ((size_t)((hidx * 64 + (t >> 5)) * 8 + (d >> 4))) * 512 +
                       ((t & 31) + ((d >> 3) & 1) * 32) * 8 + (d & 7);
          Co[idx] = (f16)outv;
        }
      }
    }
  }
}

// ---------------- Output GEMM: C = attn * wout^T, f32 out, 128x64 tiles, BK=32 ----------
__global__ __launch_bounds__(256, 2) void out_gemm_kernel(const f16* __restrict__ A,
                                                          const f16* __restrict__ B,
                                                          float* __restrict__ C) {
  __shared__ f16 As[128 * 32];
  __shared__ f16 Bs[64 * 32];
  const int tid = threadIdx.x;
  const int wave = tid >> 6, lane = tid & 63;
  const int l16 = lane & 15, quad = lane >> 4;
  const int wm = (wave >> 1) << 6, wn = (wave & 1) << 5;
  const int bm = blockIdx.y << 7, bn = blockIdx.x << 6;

  const int swg = ((lane & 3) ^ ((lane >> 3) & 3)) * 8;
  const f16* Ag = A + (size_t)(bm + wave * 32 + (lane >> 2)) * EMB + swg;
  const f16* Bg = B + (size_t)(bn + wave * 16 + (lane >> 2)) * EMB + swg;
  f16* Asl = &As[wave * 1024 + lane * 8];
  f16* Bsl = &Bs[wave * 512 + lane * 8];

  const int swr = (quad ^ ((l16 >> 1) & 3)) * 8;
  int aoff[4], boff[2];
#pragma unroll
  for (int i = 0; i < 4; i++) aoff[i] = (wm + i * 16 + l16) * 32 + swr;
#pragma unroll
  for (int i = 0; i < 2; i++) boff[i] = (wn + i * 16 + l16) * 32 + swr;

  f32x4 acc[4][2];
#pragma unroll
  for (int i = 0; i < 4; i++)
#pragma unroll
    for (int j = 0; j < 2; j++) acc[i][j] = (f32x4){0.f, 0.f, 0.f, 0.f};

  for (int k0 = 0; k0 < EMB; k0 += 32) {
    __syncthreads();
    gload16(Ag + k0, Asl);
    gload16(Ag + (size_t)16 * EMB + k0, Asl + 512);
    gload16(Bg + k0, Bsl);
    __syncthreads();
    f16x8 af[4], bf[2];
#pragma unroll
    for (int mi = 0; mi < 4; mi++) af[mi] = *(const f16x8*)&As[aoff[mi]];
#pragma unroll
    for (int ni = 0; ni < 2; ni++) bf[ni] = *(const f16x8*)&Bs[boff[ni]];
#pragma unroll
    for (int mi = 0; mi < 4; mi++)
#pragma unroll
      for (int ni = 0; ni < 2; ni++)
        acc[mi][ni] = __builtin_amdgcn_mfma_f32_16x16x32_f16(af[mi], bf[ni], acc[mi][ni], 0, 0, 0);
  }

#pragma unroll
  for (int mi = 0; mi < 4; mi++) {
#pragma unroll
    for (int ni = 0; ni < 2; ni++) {
      int row0 = bm + wm + mi * 16 + quad * 4;
      int col = bn + wn + ni * 16 + l16;
#pragma unroll
      for (int rg = 0; rg < 4; rg++)
        C[(size_t)(row0 + rg) * EMB + col] = acc[mi][ni][rg];
    }
  }
}

// ---------------- Differential attention v13: cross-step pipeline, MFMA-side lsum ------
// v11 base (no-LDS main loop, register-resident, 4 waves=(hh,qs), grid (16,32), 2/CU).
// New: (1) cross-step software pipeline — QK(step n+1) MFMAs are issued with no
// dependency on exp/pack(step n) VALU, so the two pipes overlap; buffers get a full
// iteration of load slack. (2) lsum moved to the MFMA pipe via ones-A trick:
// Osum = mfma(ones, pf, Osum) gives every row = sum_k P[k][q] (covers both hi
// halves -> epilogue shfl also gone). (3) softmax bias as loop-invariant C operand.
__global__ __launch_bounds__(256, 2) void diff_attn_v13(
    const f16* __restrict__ qbT, const f16* __restrict__ kbT, const ushort_t* __restrict__ vbT,
    const float* __restrict__ lq1, const float* __restrict__ lq2,
    const float* __restrict__ lk1, const float* __restrict__ lk2,
    const float* __restrict__ subw, f16* __restrict__ attnb) {
  const int h = blockIdx.x;  // head fastest -> heads stay L2-resident per XCD
  const int qblk = blockIdx.y;
  const int tid = threadIdx.x;
  const int wave = tid >> 6, lane = tid & 63;
  const int l32 = lane & 31, hi = lane >> 5;
  const int hh = wave >> 1, qs = wave & 1;

  __shared__ float Obuf[8192];  // 32 KB, epilogue only

  // ---- Q B-frags from qbT (coalesced tile loads) ----
  const int qrow0 = qblk * 64 + qs * 32;
  f16x8 qf[4];
  {
    const f16* qT = qbT + ((size_t)((h * 64 + qblk * 2 + qs) * 8 + hh * 4)) * 512 + lane * 8;
#pragma unroll
    for (int c = 0; c < 4; c++) qf[c] = *(const f16x8*)(qT + c * 512);
  }

  f32x16 O[4];   // [dim-tile]; col=q=l32, row=(r&3)+8*(r>>2)+4*hi
  f32x16 Osum;   // every row = sum_k P[k][q=l32] (denominator accumulator)
#pragma unroll
  for (int dt = 0; dt < 4; dt++)
#pragma unroll
    for (int s2 = 0; s2 < 16; s2++) O[dt][s2] = 0.f;
#pragma unroll
  for (int s2 = 0; s2 < 16; s2++) Osum[s2] = 0.f;

  f32x16 biasC;  // loop-invariant softmax bias as MFMA C operand
#pragma unroll
  for (int s2 = 0; s2 < 16; s2++) biasC[s2] = -28.8539008f;

  bf16x8 ones;   // bf16 1.0 x8 for the denominator MFMA
  {
    us8 o;
#pragma unroll
    for (int j = 0; j < 8; j++) o[j] = 0x3F80;
    ones = __builtin_bit_cast(bf16x8, o);
  }

  // ---- per-step fragment base pointers (advance 4096 elems per 32-key step) ----
  const f16* kT = kbT + ((size_t)(h * 64) * 8 + hh * 4) * 512 + lane * 8;
  const ushort_t* vT = vbT + (size_t)h * 262144 + lane * 8;

  auto loadK = [&](f16x8(&kr)[4], int it) {
    const f16* p = kT + (size_t)it * 4096;
#pragma unroll
    for (int c = 0; c < 4; c++) kr[c] = *(const f16x8*)(p + c * 512);
  };
  auto loadV = [&](us8(&vr)[8], int it) {
    const ushort_t* p = vT + (size_t)it * 4096;
#pragma unroll
    for (int T = 0; T < 8; T++) vr[T] = *(const us8*)(p + T * 512);
  };

  auto qk4 = [&](const f16x8(&kr)[4]) {
    f32x16 acc = __builtin_amdgcn_mfma_f32_32x32x16_f16(kr[0], qf[0], biasC, 0, 0, 0);
#pragma unroll
    for (int c = 1; c < 4; c++)
      acc = __builtin_amdgcn_mfma_f32_32x32x16_f16(kr[c], qf[c], acc, 0, 0, 0);
    return acc;
  };

  auto exppack = [&](const f32x16& acc, bf16x8(&pf)[2]) {
    float p[16];
#pragma unroll
    for (int s2 = 0; s2 < 16; s2++) p[s2] = __builtin_exp2f(acc[s2]);
#pragma unroll
    for (int c2 = 0; c2 < 2; c2++) {
      unsigned w0 = cvt_pk_bf16_2(p[8 * c2 + 0], p[8 * c2 + 1]);
      unsigned w1 = cvt_pk_bf16_2(p[8 * c2 + 2], p[8 * c2 + 3]);
      unsigned w2 = cvt_pk_bf16_2(p[8 * c2 + 4], p[8 * c2 + 5]);
      unsigned w3 = cvt_pk_bf16_2(p[8 * c2 + 6], p[8 * c2 + 7]);
      asm("v_permlane32_swap_b32 %0, %1" : "+v"(w0), "+v"(w2));
      asm("v_permlane32_swap_b32 %0, %1" : "+v"(w1), "+v"(w3));
      uint4v pw;
      pw.x = w0; pw.y = w1; pw.z = w2; pw.w = w3;
      pf[c2] = __builtin_bit_cast(bf16x8, pw);
    }
  };

  auto pv = [&](const us8(&vr)[8], const bf16x8(&pf)[2]) {
    __builtin_amdgcn_s_setprio(1);
#pragma unroll
    for (int c2 = 0; c2 < 2; c2++) {
      Osum = __builtin_amdgcn_mfma_f32_32x32x16_bf16(ones, pf[c2], Osum, 0, 0, 0);
#pragma unroll
      for (int dt = 0; dt < 4; dt++) {
        bf16x8 vf = __builtin_bit_cast(bf16x8, vr[c2 * 4 + dt]);
        O[dt] = __builtin_amdgcn_mfma_f32_32x32x16_bf16(vf, pf[c2], O[dt], 0, 0, 0);
      }
    }
    __builtin_amdgcn_s_setprio(0);
  };

  // ---- cross-step pipeline: kA/vA = even steps, kB/vB = odd steps ----
  f16x8 kA[4], kB[4];
  us8 vA[8], vB[8];
  loadK(kA, 0);
  loadV(vA, 0);
  loadK(kB, 1);
  loadV(vB, 1);
  f32x16 acc_e = qk4(kA);  // step 0
  loadK(kA, 2);

  for (int it = 0; it < 64; it += 2) {
    // QK(it+1) — MFMA, independent of the VALU below
    f32x16 acc_o = qk4(kB);
    loadK(kB, (it + 3 < 64) ? it + 3 : 63);
    // exp/pack(it) — VALU, overlaps acc_o's MFMA chain
    bf16x8 pf[2];
    exppack(acc_e, pf);
    pv(vA, pf);  // MFMA step it
    loadV(vA, (it + 2 < 64) ? it + 2 : 63);
    // QK(it+2) — MFMA (kA loaded a full iteration ago), overlaps exppack(acc_o)
    acc_e = qk4(kA);
    loadK(kA, (it + 4 < 64) ? it + 4 : 63);
    bf16x8 pg[2];
    exppack(acc_o, pg);
    pv(vB, pg);  // MFMA step it+1
    loadV(vB, (it + 3 < 64) ? it + 3 : 63);
  }

  // ---- lambda ----
  float d1 = 0.f, d2 = 0.f;
  for (int i = 0; i < 64; i++) {
    d1 += lq1[i] * lk1[i];
    d2 += lq2[i] * lk2[i];
  }
  const float lam = __expf(d1) - __expf(d2) + 0.783605767f;

  // ---- denominator directly from Osum (all rows equal; covers both hi halves) ----
  const float inv = (hh == 0) ? (1.f / Osum[0]) : (lam / Osum[0]);

  // ---- cross-half combine through LDS ----
  if (hh == 1) {
#pragma unroll
    for (int dt = 0; dt < 4; dt++)
#pragma unroll
      for (int rq = 0; rq < 4; rq++) {
        f32x4 v;
#pragma unroll
        for (int rg = 0; rg < 4; rg++) v[rg] = O[dt][rq * 4 + rg] * inv;
        *(f32x4*)&Obuf[(((qs * 4 + dt) * 4 + rq) * 64 + lane) * 4] = v;
      }
  }
  __syncthreads();
  if (hh == 0) {
    float a[4][16];
    float ms = 0.f;
#pragma unroll
    for (int dt = 0; dt < 4; dt++)
#pragma unroll
      for (int rq = 0; rq < 4; rq++) {
        f32x4 o1 = *(const f32x4*)&Obuf[(((qs * 4 + dt) * 4 + rq) * 64 + lane) * 4];
#pragma unroll
        for (int rg = 0; rg < 4; rg++) {
          float v = O[dt][rq * 4 + rg] * inv - o1[rg];
          a[dt][rq * 4 + rg] = v;
          ms += v * v;
        }
      }
    ms += __shfl_xor(ms, 32);
    const float rms = rsqrtf(ms * (1.f / 128.f) + 1e-5f);
    const int t_g = qrow0 + l32;
#pragma unroll
    for (int dt = 0; dt < 4; dt++)
#pragma unroll
      for (int rq = 0; rq < 4; rq++) {
        f32x4 sw = *(const f32x4*)(subw + dt * 32 + rq * 8 + hi * 4);
        f16x4 o;
#pragma unroll
        for (int rg = 0; rg < 4; rg++) o[rg] = (f16)(a[dt][rq * 4 + rg] * rms * sw[rg]);
        *(f16x4*)(attnb + (size_t)t_g * EMB + h * 128 + dt * 32 + rq * 8 + hi * 4) = o;
      }
  }
}

// ---------------- launcher ----------------
extern "C" void kernel_launch(void* const* d_in, const int* in_sizes, int n_in,
                              void* d_out, int out_size, void* d_ws, size_t ws_size,
                              hipStream_t stream) {
  const float* x    = (const float*)d_in[0];
  const float* wq   = (const float*)d_in[1];
  const float* wk   = (const float*)d_in[2];
  const float* wv   = (const float*)d_in[3];
  const float* wout = (const float*)d_in[4];
  const float* lq1  = (const float*)d_in[5];
  const float* lq2  = (const float*)d_in[6];
  const float* lk1  = (const float*)d_in[7];
  const float* lk2  = (const float*)d_in[8];
  const float* subw = (const float*)d_in[9];
  float* out = (float*)d_out;

  char* ws = (char*)d_ws;
  const size_t MB = 1024 * 1024;
  f16* xb    = (f16*)(ws + 0 * MB);
  f16* wqb   = (f16*)(ws + 8 * MB);
  f16* wkb   = (f16*)(ws + 16 * MB);
  f16* wvb   = (f16*)(ws + 24 * MB);
  f16* woutb = (f16*)(ws + 32 * MB);
  f16* qbT   = (f16*)(ws + 40 * MB);  // f16, fragment-tiled per head (rope'd, scaled)
  f16* kbT   = (f16*)(ws + 48 * MB);  // f16, fragment-tiled per head (rope'd)
  ushort_t* vbT = (ushort_t*)(ws + 56 * MB);  // bf16, fragment-tiled per head
  f16* attnb = (f16*)(ws + 64 * MB);
  float* cosT = (float*)(ws + 72 * MB);
  float* sinT = (float*)(ws + 72 * MB + 262144);

  dim3 b256(256);
  cvt5_kernel<<<5 * 4096, b256, 0, stream>>>(x, wq, wk, wv, wout, xb, wqb, wkb, wvb, woutb);
  rope_table_kernel<<<256, b256, 0, stream>>>(cosT, sinT);

  proj_gemm_kernel<<<dim3(16, 16, 3), b256, 0, stream>>>(xb, wqb, wkb, wvb, cosT, sinT, qbT, kbT,
                                                         vbT);

  diff_attn_v13<<<dim3(16, 32), b256, 0, stream>>>(qbT, kbT, vbT, lq1, lq2, lk1, lk2, subw,
                                                   attnb);

  out_gemm_kernel<<<dim3(32, 16), b256, 0, stream>>>(attnb, woutb, out);
}

// Round 10
// 287.732 us; speedup vs baseline: 2.6074x; 1.1382x over previous
//
#include <hip/hip_runtime.h>
#include <math.h>

#define SEQ 2048
#define EMB 2048

typedef _Float16 f16;
typedef unsigned short ushort_t;
typedef __attribute__((ext_vector_type(2))) _Float16 f16x2;
typedef __attribute__((ext_vector_type(4))) _Float16 f16x4;
typedef __attribute__((ext_vector_type(8))) _Float16 f16x8;
typedef __attribute__((ext_vector_type(4))) float f32x4;
typedef __attribute__((ext_vector_type(16))) float f32x16;
typedef __attribute__((ext_vector_type(8))) short bf16x8;
typedef __attribute__((ext_vector_type(4))) unsigned short us4;
typedef __attribute__((ext_vector_type(8))) unsigned short us8;
typedef __attribute__((ext_vector_type(4))) unsigned int uint4v;

// async global->LDS, 16B per lane; LDS dest is lane-contiguous from lane0's ptr
__device__ __forceinline__ void gload16(const void* g, void* l) {
  __builtin_amdgcn_global_load_lds((const __attribute__((address_space(1))) unsigned int*)g,
                                   (__attribute__((address_space(3))) unsigned int*)l, 16, 0, 0);
}

__device__ __forceinline__ ushort_t f32_to_bf16(float f) {
  unsigned int u = __builtin_bit_cast(unsigned int, f);
  u += 0x7FFFu + ((u >> 16) & 1u);
  return (ushort_t)(u >> 16);
}

// packed f32x2 -> bf16x2 in one VALU op (RNE)
__device__ __forceinline__ unsigned cvt_pk_bf16_2(float lo, float hi) {
  unsigned r;
  asm("v_cvt_pk_bf16_f32 %0, %1, %2" : "=v"(r) : "v"(lo), "v"(hi));
  return r;
}

// ---------------- fp32 -> fp16 conversion, 5 tensors in one launch ----------------
__global__ __launch_bounds__(256) void cvt5_kernel(const float* __restrict__ i0,
                                                   const float* __restrict__ i1,
                                                   const float* __restrict__ i2,
                                                   const float* __restrict__ i3,
                                                   const float* __restrict__ i4,
                                                   f16* __restrict__ o0, f16* __restrict__ o1,
                                                   f16* __restrict__ o2, f16* __restrict__ o3,
                                                   f16* __restrict__ o4) {
  int b = blockIdx.x;
  int z = b >> 12;
  const float* in = (z == 0) ? i0 : (z == 1) ? i1 : (z == 2) ? i2 : (z == 3) ? i3 : i4;
  f16* out = (z == 0) ? o0 : (z == 1) ? o1 : (z == 2) ? o2 : (z == 3) ? o3 : o4;
  int i = ((b & 4095) * 256 + threadIdx.x) * 4;
  f32x4 v = *(const f32x4*)(in + i);
  *(f16x4*)(out + i) = __builtin_convertvector(v, f16x4);
}

// ---------------- RoPE tables (double precision, matches numpy) ----------------
__global__ __launch_bounds__(256) void rope_table_kernel(float* __restrict__ cosT,
                                                         float* __restrict__ sinT) {
  int id = blockIdx.x * 256 + threadIdx.x;
  int t = id >> 5, i = id & 31;
  double inv = pow(10000.0, -(double)i / 32.0);
  double ang = (double)t * inv;
  cosT[id] = (float)cos(ang);
  sinT[id] = (float)sin(ang);
}

// ---------------- Fused projection GEMM + RoPE epilogue, BK=64 (split sub-buffers) ----
// As[g]/Bs[g] each keep the proven 128x32 conflict-free layout (linear gload16 dest,
// swizzled read); one barrier pair per 64-K step (32 total, was 64).
// z=0 -> Q fragment-tiled qbT (rope + sqrt(128)*log2e scale)
// z=1 -> K fragment-tiled kbT (rope)
// z=2 -> V fragment-tiled vbT (bf16)
// Fragment layouts (all MFMA 32x32x16 operand tiles, 512 elems = 1 KB each):
//  qbT/kbT idx for X[t][h*128+d]:
//    ((h*64 + (t>>5))*8 + (d>>4))*512 + ((t&31) + ((d>>3)&1)*32)*8 + (d&7)
//  vbT idx for V[t][h*128+d]:
//    (((h*32+(t>>6))*4+((t>>4)&3))*4+(d>>5))*512 + (((t>>3)&1)*32 + (d&31))*8 + (t&7)
__global__ __launch_bounds__(256, 3) void proj_gemm_kernel(
    const f16* __restrict__ A, const f16* __restrict__ B0, const f16* __restrict__ B1,
    const f16* __restrict__ B2, const float* __restrict__ cosT, const float* __restrict__ sinT,
    f16* __restrict__ qout, f16* __restrict__ kout, ushort_t* __restrict__ vtout) {
  const int z = blockIdx.z;
  const f16* __restrict__ B = (z == 0) ? B0 : ((z == 1) ? B1 : B2);
  __shared__ f16 As[2][128 * 32];  // 16 KB (K-half sub-buffers)
  __shared__ f16 Bs[2][128 * 32];  // 16 KB
  const int tid = threadIdx.x;
  const int wave = tid >> 6, lane = tid & 63;
  const int l16 = lane & 15, quad = lane >> 4;
  const int wm = (wave >> 1) << 6, wn = (wave & 1) << 6;
  const int bm = blockIdx.y << 7, bn = blockIdx.x << 7;

  const int swg = ((lane & 3) ^ ((lane >> 3) & 3)) * 8;
  const f16* Ag = A + (size_t)(bm + wave * 32 + (lane >> 2)) * EMB + swg;
  const f16* Bg = B + (size_t)(bn + wave * 32 + (lane >> 2)) * EMB + swg;
  const int sl = wave * 1024 + lane * 8;

  const int swr = (quad ^ ((l16 >> 1) & 3)) * 8;
  int aoff[4], boff[4];
#pragma unroll
  for (int i = 0; i < 4; i++) {
    aoff[i] = (wm + i * 16 + l16) * 32 + swr;
    boff[i] = (wn + i * 16 + l16) * 32 + swr;
  }

  f32x4 acc[4][4];
#pragma unroll
  for (int i = 0; i < 4; i++)
#pragma unroll
    for (int j = 0; j < 4; j++) acc[i][j] = (f32x4){0.f, 0.f, 0.f, 0.f};

  for (int k0 = 0; k0 < EMB; k0 += 64) {
    __syncthreads();
    // K-half 0 (cols k0..k0+31) and K-half 1 (cols k0+32..k0+63)
    gload16(Ag + k0, &As[0][sl]);
    gload16(Ag + (size_t)16 * EMB + k0, &As[0][sl + 512]);
    gload16(Ag + k0 + 32, &As[1][sl]);
    gload16(Ag + (size_t)16 * EMB + k0 + 32, &As[1][sl + 512]);
    gload16(Bg + k0, &Bs[0][sl]);
    gload16(Bg + (size_t)16 * EMB + k0, &Bs[0][sl + 512]);
    gload16(Bg + k0 + 32, &Bs[1][sl]);
    gload16(Bg + (size_t)16 * EMB + k0 + 32, &Bs[1][sl + 512]);
    __syncthreads();
#pragma unroll
    for (int g = 0; g < 2; g++) {
      f16x8 af[4], bf[4];
#pragma unroll
      for (int mi = 0; mi < 4; mi++) af[mi] = *(const f16x8*)&As[g][aoff[mi]];
#pragma unroll
      for (int ni = 0; ni < 4; ni++) bf[ni] = *(const f16x8*)&Bs[g][boff[ni]];
#pragma unroll
      for (int mi = 0; mi < 4; mi++)
#pragma unroll
        for (int ni = 0; ni < 4; ni++)
          acc[mi][ni] =
              __builtin_amdgcn_mfma_f32_16x16x32_f16(af[mi], bf[ni], acc[mi][ni], 0, 0, 0);
    }
  }

  if (z == 2) {
#pragma unroll
    for (int mi = 0; mi < 4; mi++) {
#pragma unroll
      for (int ni = 0; ni < 4; ni++) {
        int row0 = bm + wm + mi * 16 + quad * 4;  // C/D: col=l16, row=quad*4+reg
        int col = bn + wn + ni * 16 + l16;
        us4 o;
#pragma unroll
        for (int rg = 0; rg < 4; rg++) o[rg] = f32_to_bf16(acc[mi][ni][rg]);
        int hidx = col >> 7, d = col & 127, t = row0;  // t..t+3 share all bits above t&7
        size_t idx = ((((size_t)hidx * 32 + (t >> 6)) * 4 + ((t >> 4) & 3)) * 4 + (d >> 5)) * 512 +
                     (((t >> 3) & 1) * 32 + (d & 31)) * 8 + (t & 7);
        *(us4*)&vtout[idx] = o;
      }
    }
  } else {
    f16* Co = (z == 0) ? qout : kout;
    const float scale = (z == 0) ? 16.3222307f : 1.0f;  // sqrt(128)*log2(e) folded into q
#pragma unroll
    for (int mi = 0; mi < 4; mi++) {
#pragma unroll
      for (int ni = 0; ni < 4; ni++) {
        int row0 = bm + wm + mi * 16 + quad * 4;
        int col = bn + wn + ni * 16 + l16;
        int i_r = (col & 63) >> 1;
        int odd = col & 1;  // = l16 & 1 (bn, wn, ni*16 even)
        int hidx = col >> 7, d = col & 127;
#pragma unroll
        for (int rg = 0; rg < 4; rg++) {
          int t = row0 + rg;
          float c = cosT[(t << 5) + i_r] * scale;
          float s = sinT[(t << 5) + i_r] * scale;
          float own = acc[mi][ni][rg];
          float other = __shfl_xor(own, 1);
          float xr = odd ? other : own;
          float xi = odd ? own : other;
          float outv = odd ? (xr * s + xi * c) : (xr * c - xi * s);
          size_t idx = ((size_t)((hidx * 64 + (t >> 5)) * 8 + (d >> 4))) * 512 +
                       ((t & 31) + ((d >> 3) & 1) * 32) * 8 + (d & 7);
          Co[idx] = (f16)outv;
        }
      }
    }
  }
}

// ---------------- Output GEMM: C = attn * wout^T, f32 out, 128x64 tiles, BK=64 ----------
__global__ __launch_bounds__(256, 2) void out_gemm_kernel(const f16* __restrict__ A,
                                                          const f16* __restrict__ B,
                                                          float* __restrict__ C) {
  __shared__ f16 As[2][128 * 32];  // 16 KB
  __shared__ f16 Bs[2][64 * 32];   // 8 KB
  const int tid = threadIdx.x;
  const int wave = tid >> 6, lane = tid & 63;
  const int l16 = lane & 15, quad = lane >> 4;
  const int wm = (wave >> 1) << 6, wn = (wave & 1) << 5;
  const int bm = blockIdx.y << 7, bn = blockIdx.x << 6;

  const int swg = ((lane & 3) ^ ((lane >> 3) & 3)) * 8;
  const f16* Ag = A + (size_t)(bm + wave * 32 + (lane >> 2)) * EMB + swg;
  const f16* Bg = B + (size_t)(bn + wave * 16 + (lane >> 2)) * EMB + swg;
  const int sla = wave * 1024 + lane * 8;
  const int slb = wave * 512 + lane * 8;

  const int swr = (quad ^ ((l16 >> 1) & 3)) * 8;
  int aoff[4], boff[2];
#pragma unroll
  for (int i = 0; i < 4; i++) aoff[i] = (wm + i * 16 + l16) * 32 + swr;
#pragma unroll
  for (int i = 0; i < 2; i++) boff[i] = (wn + i * 16 + l16) * 32 + swr;

  f32x4 acc[4][2];
#pragma unroll
  for (int i = 0; i < 4; i++)
#pragma unroll
    for (int j = 0; j < 2; j++) acc[i][j] = (f32x4){0.f, 0.f, 0.f, 0.f};

  for (int k0 = 0; k0 < EMB; k0 += 64) {
    __syncthreads();
    gload16(Ag + k0, &As[0][sla]);
    gload16(Ag + (size_t)16 * EMB + k0, &As[0][sla + 512]);
    gload16(Ag + k0 + 32, &As[1][sla]);
    gload16(Ag + (size_t)16 * EMB + k0 + 32, &As[1][sla + 512]);
    gload16(Bg + k0, &Bs[0][slb]);
    gload16(Bg + k0 + 32, &Bs[1][slb]);
    __syncthreads();
#pragma unroll
    for (int g = 0; g < 2; g++) {
      f16x8 af[4], bf[2];
#pragma unroll
      for (int mi = 0; mi < 4; mi++) af[mi] = *(const f16x8*)&As[g][aoff[mi]];
#pragma unroll
      for (int ni = 0; ni < 2; ni++) bf[ni] = *(const f16x8*)&Bs[g][boff[ni]];
#pragma unroll
      for (int mi = 0; mi < 4; mi++)
#pragma unroll
        for (int ni = 0; ni < 2; ni++)
          acc[mi][ni] =
              __builtin_amdgcn_mfma_f32_16x16x32_f16(af[mi], bf[ni], acc[mi][ni], 0, 0, 0);
    }
  }

#pragma unroll
  for (int mi = 0; mi < 4; mi++) {
#pragma unroll
    for (int ni = 0; ni < 2; ni++) {
      int row0 = bm + wm + mi * 16 + quad * 4;
      int col = bn + wn + ni * 16 + l16;
#pragma unroll
      for (int rg = 0; rg < 4; rg++)
        C[(size_t)(row0 + rg) * EMB + col] = acc[mi][ni][rg];
    }
  }
}

// ---------------- Differential attention v11: no-LDS, register-resident pipeline -------
// (reverted to the best-measured variant: 88 us, VGPR 128, zero conflicts)
// 256 threads, 4 waves = (hh=wave>>1, qs=wave&1), 32 q-rows per wave.
// Q/K/V all fragment-tiled in global (coalesced 1KB tile loads). Main loop has NO
// LDS, NO barriers: each wave ping-pongs K(4xf16x8)+V(8xus8) register buffers,
// prefetching step it+2 while computing it. 64 steps of 32 keys.
// QK^T via mfma_32x32x16_f16 (S^T: col=lane&31=q, row=(r&3)+8*(r>>2)+4*hi=key);
// P -> bf16 PV B-frags in registers via v_cvt_pk_bf16_f32 + permlane32_swap.
__global__ __launch_bounds__(256, 2) void diff_attn_v11(
    const f16* __restrict__ qbT, const f16* __restrict__ kbT, const ushort_t* __restrict__ vbT,
    const float* __restrict__ lq1, const float* __restrict__ lq2,
    const float* __restrict__ lk1, const float* __restrict__ lk2,
    const float* __restrict__ subw, f16* __restrict__ attnb) {
  const int h = blockIdx.x;  // head fastest -> heads stay L2-resident per XCD
  const int qblk = blockIdx.y;
  const int tid = threadIdx.x;
  const int wave = tid >> 6, lane = tid & 63;
  const int l32 = lane & 31, hi = lane >> 5;
  const int hh = wave >> 1, qs = wave & 1;

  __shared__ float Obuf[8192];  // 32 KB, epilogue only

  // ---- Q B-frags from qbT (coalesced tile loads) ----
  const int qrow0 = qblk * 64 + qs * 32;
  f16x8 qf[4];
  {
    const f16* qT = qbT + ((size_t)((h * 64 + qblk * 2 + qs) * 8 + hh * 4)) * 512 + lane * 8;
#pragma unroll
    for (int c = 0; c < 4; c++) qf[c] = *(const f16x8*)(qT + c * 512);
  }

  f32x16 O[4];  // [dim-tile]; col=q=l32, row=(r&3)+8*(r>>2)+4*hi = dim within tile
#pragma unroll
  for (int dt = 0; dt < 4; dt++)
#pragma unroll
    for (int s2 = 0; s2 < 16; s2++) O[dt][s2] = 0.f;
  float lsum = 0.f;

  // ---- per-step fragment base pointers (advance 4096 elems per 32-key step) ----
  const f16* kT = kbT + ((size_t)(h * 64) * 8 + hh * 4) * 512 + lane * 8;
  const ushort_t* vT = vbT + (size_t)h * 262144 + lane * 8;

  auto loadK = [&](f16x8(&kr)[4], int it) {
    const f16* p = kT + (size_t)it * 4096;
#pragma unroll
    for (int c = 0; c < 4; c++) kr[c] = *(const f16x8*)(p + c * 512);
  };
  auto loadV = [&](us8(&vr)[8], int it) {
    const ushort_t* p = vT + (size_t)it * 4096;
#pragma unroll
    for (int T = 0; T < 8; T++) vr[T] = *(const us8*)(p + T * 512);
  };

  auto compute = [&](const f16x8(&kr)[4], const us8(&vr)[8]) {
    f32x16 acc;
#pragma unroll
    for (int s2 = 0; s2 < 16; s2++) acc[s2] = -28.8539008f;  // softmax bias in C-init
#pragma unroll
    for (int c = 0; c < 4; c++)
      acc = __builtin_amdgcn_mfma_f32_32x32x16_f16(kr[c], qf[c], acc, 0, 0, 0);
    float p[16];
#pragma unroll
    for (int s2 = 0; s2 < 16; s2++) p[s2] = __builtin_exp2f(acc[s2]);
    lsum += (((p[0] + p[1]) + (p[2] + p[3])) + ((p[4] + p[5]) + (p[6] + p[7]))) +
            (((p[8] + p[9]) + (p[10] + p[11])) + ((p[12] + p[13]) + (p[14] + p[15])));
    bf16x8 pf[2];
#pragma unroll
    for (int c2 = 0; c2 < 2; c2++) {
      unsigned w0 = cvt_pk_bf16_2(p[8 * c2 + 0], p[8 * c2 + 1]);
      unsigned w1 = cvt_pk_bf16_2(p[8 * c2 + 2], p[8 * c2 + 3]);
      unsigned w2 = cvt_pk_bf16_2(p[8 * c2 + 4], p[8 * c2 + 5]);
      unsigned w3 = cvt_pk_bf16_2(p[8 * c2 + 6], p[8 * c2 + 7]);
      asm("v_permlane32_swap_b32 %0, %1" : "+v"(w0), "+v"(w2));
      asm("v_permlane32_swap_b32 %0, %1" : "+v"(w1), "+v"(w3));
      uint4v pw;
      pw.x = w0; pw.y = w1; pw.z = w2; pw.w = w3;
      pf[c2] = __builtin_bit_cast(bf16x8, pw);
    }
    __builtin_amdgcn_s_setprio(1);
#pragma unroll
    for (int c2 = 0; c2 < 2; c2++) {
#pragma unroll
      for (int dt = 0; dt < 4; dt++) {
        bf16x8 vf = __builtin_bit_cast(bf16x8, vr[c2 * 4 + dt]);
        O[dt] = __builtin_amdgcn_mfma_f32_32x32x16_bf16(vf, pf[c2], O[dt], 0, 0, 0);
      }
    }
    __builtin_amdgcn_s_setprio(0);
  };

  // ---- register ping-pong pipeline, prefetch 2 steps ahead ----
  f16x8 kA[4], kB[4];
  us8 vA[8], vB[8];
  loadK(kA, 0);
  loadV(vA, 0);
  loadK(kB, 1);
  loadV(vB, 1);
  for (int it = 0; it < 64; it += 2) {
    compute(kA, vA);
    if (it + 2 < 64) {
      loadK(kA, it + 2);
      loadV(vA, it + 2);
    }
    compute(kB, vB);
    if (it + 3 < 64) {
      loadK(kB, it + 3);
      loadV(vB, it + 3);
    }
  }

  // ---- lambda ----
  float d1 = 0.f, d2 = 0.f;
  for (int i = 0; i < 64; i++) {
    d1 += lq1[i] * lk1[i];
    d2 += lq2[i] * lk2[i];
  }
  const float lam = __expf(d1) - __expf(d2) + 0.783605767f;

  // ---- per-q softmax denominator (lane + partner lane cover all keys) ----
  float s = lsum + __shfl_xor(lsum, 32);
  const float inv = (hh == 0) ? (1.f / s) : (lam / s);

  // ---- cross-half combine through LDS ----
  if (hh == 1) {
#pragma unroll
    for (int dt = 0; dt < 4; dt++)
#pragma unroll
      for (int rq = 0; rq < 4; rq++) {
        f32x4 v;
#pragma unroll
        for (int rg = 0; rg < 4; rg++) v[rg] = O[dt][rq * 4 + rg] * inv;
        *(f32x4*)&Obuf[(((qs * 4 + dt) * 4 + rq) * 64 + lane) * 4] = v;
      }
  }
  __syncthreads();
  if (hh == 0) {
    float a[4][16];
    float ms = 0.f;
#pragma unroll
    for (int dt = 0; dt < 4; dt++)
#pragma unroll
      for (int rq = 0; rq < 4; rq++) {
        f32x4 o1 = *(const f32x4*)&Obuf[(((qs * 4 + dt) * 4 + rq) * 64 + lane) * 4];
#pragma unroll
        for (int rg = 0; rg < 4; rg++) {
          float v = O[dt][rq * 4 + rg] * inv - o1[rg];
          a[dt][rq * 4 + rg] = v;
          ms += v * v;
        }
      }
    ms += __shfl_xor(ms, 32);
    const float rms = rsqrtf(ms * (1.f / 128.f) + 1e-5f);
    const int t_g = qrow0 + l32;
#pragma unroll
    for (int dt = 0; dt < 4; dt++)
#pragma unroll
      for (int rq = 0; rq < 4; rq++) {
        f32x4 sw = *(const f32x4*)(subw + dt * 32 + rq * 8 + hi * 4);
        f16x4 o;
#pragma unroll
        for (int rg = 0; rg < 4; rg++) o[rg] = (f16)(a[dt][rq * 4 + rg] * rms * sw[rg]);
        *(f16x4*)(attnb + (size_t)t_g * EMB + h * 128 + dt * 32 + rq * 8 + hi * 4) = o;
      }
  }
}

// ---------------- launcher ----------------
extern "C" void kernel_launch(void* const* d_in, const int* in_sizes, int n_in,
                              void* d_out, int out_size, void* d_ws, size_t ws_size,
                              hipStream_t stream) {
  const float* x    = (const float*)d_in[0];
  const float* wq   = (const float*)d_in[1];
  const float* wk   = (const float*)d_in[2];
  const float* wv   = (const float*)d_in[3];
  const float* wout = (const float*)d_in[4];
  const float* lq1  = (const float*)d_in[5];
  const float* lq2  = (const float*)d_in[6];
  const float* lk1  = (const float*)d_in[7];
  const float* lk2  = (const float*)d_in[8];
  const float* subw = (const float*)d_in[9];
  float* out = (float*)d_out;

  char* ws = (char*)d_ws;
  const size_t MB = 1024 * 1024;
  f16* xb    = (f16*)(ws + 0 * MB);
  f16* wqb   = (f16*)(ws + 8 * MB);
  f16* wkb   = (f16*)(ws + 16 * MB);
  f16* wvb   = (f16*)(ws + 24 * MB);
  f16* woutb = (f16*)(ws + 32 * MB);
  f16* qbT   = (f16*)(ws + 40 * MB);  // f16, fragment-tiled per head (rope'd, scaled)
  f16* kbT   = (f16*)(ws + 48 * MB);  // f16, fragment-tiled per head (rope'd)
  ushort_t* vbT = (ushort_t*)(ws + 56 * MB);  // bf16, fragment-tiled per head
  f16* attnb = (f16*)(ws + 64 * MB);
  float* cosT = (float*)(ws + 72 * MB);
  float* sinT = (float*)(ws + 72 * MB + 262144);

  dim3 b256(256);
  cvt5_kernel<<<5 * 4096, b256, 0, stream>>>(x, wq, wk, wv, wout, xb, wqb, wkb, wvb, woutb);
  rope_table_kernel<<<256, b256, 0, stream>>>(cosT, sinT);

  proj_gemm_kernel<<<dim3(16, 16, 3), b256, 0, stream>>>(xb, wqb, wkb, wvb, cosT, sinT, qbT, kbT,
                                                         vbT);

  diff_attn_v11<<<dim3(16, 32), b256, 0, stream>>>(qbT, kbT, vbT, lq1, lq2, lk1, lk2, subw,
                                                   attnb);

  out_gemm_kernel<<<dim3(32, 16), b256, 0, stream>>>(attnb, woutb, out);
}